// Round 19
// baseline (37.531 us; speedup 1.0000x reference)
//
#include <hip/hip_runtime.h>

#define BATCH  4
#define NPTS   4096
#define NSKEL  100
#define KNN    10
#define KL     2                  // per-lane list length
#define QPB    64                 // queries per block (32 groups x 2)
#define CPT    128                // candidates per thread (32 chunks cover 4096)
#define CPAD   129                // padded chunk stride in float4s (129%8=1: bank de-conflict)
#define BIG    3.0e38f

typedef float    f32x2 __attribute__((ext_vector_type(2)));
typedef unsigned u32x2 __attribute__((ext_vector_type(2)));

__device__ __forceinline__ f32x2 sp2(float v) { f32x2 r; r.x = v; r.y = v; return r; }

__device__ __forceinline__ float med3f(float a, float b, float c) {
#if __has_builtin(__builtin_amdgcn_fmed3f)
    return __builtin_amdgcn_fmed3f(a, b, c);
#else
    float d;
    asm("v_med3_f32 %0, %1, %2, %3" : "=v"(d) : "v"(a), "v"(b), "v"(c));
    return d;
#endif
}

#define CE(a,i,j) do { float _lo = fminf(a[i],a[j]); a[j] = fmaxf(a[i],a[j]); a[i] = _lo; } while (0)
// Sorts any (cyclically-)bitonic 10-seq (validated R3-R18, absmax 0 throughout)
#define SORT10(c) do { \
    CE(c,0,8); CE(c,1,9); \
    CE(c,2,6); CE(c,3,7); CE(c,4,8); CE(c,5,9); \
    CE(c,2,4); CE(c,3,5); CE(c,6,8); CE(c,7,9); CE(c,0,1); \
    CE(c,2,3); CE(c,4,5); CE(c,6,7); CE(c,8,9); } while (0)
// Bitonic merger BM(8): sorts any bitonic 8-seq (3 stages, 12 CE)
#define BM8(c) do { \
    CE(c,0,4); CE(c,1,5); CE(c,2,6); CE(c,3,7); \
    CE(c,0,2); CE(c,1,3); CE(c,4,6); CE(c,5,7); \
    CE(c,0,1); CE(c,2,3); CE(c,4,5); CE(c,6,7); } while (0)
// Bitonic merger BM(4): sorts any bitonic 4-seq (2 stages, 4 CE)
#define BM4(c) do { \
    CE(c,0,2); CE(c,1,3); \
    CE(c,0,1); CE(c,2,3); } while (0)

// Half-cleaner merge of two ascending 10-lists (keep 10 smallest) + re-sort.
__device__ __forceinline__ void merge_round(float l[KNN], int mask) {
    float c[KNN];
#pragma unroll
    for (int i = 0; i < KNN; ++i) {
        float o = __shfl_xor(l[KNN - 1 - i], mask, 64);
        c[i] = fminf(l[i], o);
    }
    SORT10(c);
#pragma unroll
    for (int i = 0; i < KNN; ++i) l[i] = c[i];
}

// padded float4 index for global point id i (chunk i>>7 gets +1 float4 each)
#define PIDX(i) ((i) + ((i) >> 7))

__global__ __launch_bounds__(1024) void voronoi_kernel(const float* __restrict__ xyz,
                                                       const float* __restrict__ skel,
                                                       float* __restrict__ out) {
    __shared__ float4 spts[NPTS + 32];   // AoS x,y,z,|p|^2, padded: 64.5 KB
    __shared__ float4 sskl[NSKEL];
    __shared__ float  qlists[QPB][KNN];
    __shared__ float  part[16];

    const int tid = threadIdx.x;
    const int b   = blockIdx.x >> 6;           // 64 blocks per batch
    const int qb  = (blockIdx.x & 63) * QPB;   // 64 queries per block
    const float* xb = xyz  + (size_t)b * NPTS * 6;
    const float* sb = skel + (size_t)b * NSKEL * 3;

    // Stage 2 points per iter via 3 coalesced float4 loads (2 iterations)
    for (int p2 = tid; p2 < NPTS / 2; p2 += 1024) {
        const float4* row = (const float4*)(xb + p2 * 12);
        float4 A = row[0], Bv = row[1], Cv = row[2];
        int i0 = 2 * p2;           // even: i0, i0+1 share a chunk
        spts[PIDX(i0)]     = make_float4(A.x, A.y, A.z,
                                         fmaf(A.z, A.z, fmaf(A.y, A.y, A.x * A.x)));
        spts[PIDX(i0 + 1)] = make_float4(Bv.z, Bv.w, Cv.x,
                                         fmaf(Cv.x, Cv.x, fmaf(Bv.w, Bv.w, Bv.z * Bv.z)));
    }
    if (tid < NSKEL) {
        float x = sb[tid*3+0], y = sb[tid*3+1], z = sb[tid*3+2];
        sskl[tid] = make_float4(x, y, z, x*x + y*y + z*z);
    }
    __syncthreads();

    const int split = tid & 31;
    const int group = tid >> 5;            // 0..31
    const int q0i   = qb + group * 2;
    const float4 Q0 = spts[PIDX(q0i)];
    const float4 Q1 = spts[PIDX(q0i + 1)];
    // score = |c|^2 - 2 q.c (monotone map of d2; d2 gap == score gap)
    // Packed over the 2 queries: lane .x = q0, lane .y = q1.
    const f32x2 nX = {-2.f*Q0.x, -2.f*Q1.x};
    const f32x2 nY = {-2.f*Q0.y, -2.f*Q1.y};
    const f32x2 nZ = {-2.f*Q0.z, -2.f*Q1.z};

    f32x2 Lmin = {BIG, BIG};       // packed l[0] for (q0,q1)
    float l0b = BIG, l1b = BIG;    // l[1] slots (scalar; med3 not packable)

    const int ch = split;                  // chunk 0..31
    const unsigned jbc = (unsigned)(ch << 7);
    const unsigned HMASK = 0xFFFFF000u;
    const float4* chunk = spts + ch * CPAD;  // base bank phase-distinct per 8 ch

    // Fully-unrolled scan; 1 ds_read_b128 per candidate; packed-FP32 score
    // chain (v_pk_fma_f32, splats via op_sel) computes both queries at once.
#pragma unroll
    for (int g = 0; g < CPT; ++g) {
        float4 cc = chunk[g];
        f32x2 S = __builtin_elementwise_fma(nZ, sp2(cc.z),
                  __builtin_elementwise_fma(nY, sp2(cc.y),
                  __builtin_elementwise_fma(nX, sp2(cc.x), sp2(cc.w))));
        u32x2 U = (__builtin_bit_cast(u32x2, S) & HMASK) | (jbc | (unsigned)g);
        f32x2 F = __builtin_bit_cast(f32x2, U);
        // KL=2 branchless insert (slots use OLD values)
        l0b  = med3f(F.x, Lmin.x, l0b);
        l1b  = med3f(F.y, Lmin.y, l1b);
        Lmin = __builtin_elementwise_min(F, Lmin);
    }

    float l0[KL], l1[KL];
    l0[0] = Lmin.x; l0[1] = l0b;
    l1[0] = Lmin.y; l1[1] = l1b;

    // ---- mask-1: concat my asc-2 + neighbor desc-2 (both queries), select
    //      parity, then ONE BM4 -> sorted-4 for my query over 256 cands ----
    float d0[4], d1[4];
    d0[0] = l0[0]; d0[1] = l0[1];
    d0[2] = __shfl_xor(l0[1], 1, 64);
    d0[3] = __shfl_xor(l0[0], 1, 64);
    d1[0] = l1[0]; d1[1] = l1[1];
    d1[2] = __shfl_xor(l1[1], 1, 64);
    d1[3] = __shfl_xor(l1[0], 1, 64);
    const int sel = split & 1;
    float a4[4];
#pragma unroll
    for (int k = 0; k < 4; ++k) a4[k] = sel ? d1[k] : d0[k];
    BM4(a4);

    // ---- mask-2: concat two asc-4s -> bitonic-8 -> BM8 (sorted-8, 512 cands)
    float c8[8];
    c8[0] = a4[0]; c8[1] = a4[1]; c8[2] = a4[2]; c8[3] = a4[3];
    c8[4] = __shfl_xor(a4[3], 2, 64);
    c8[5] = __shfl_xor(a4[2], 2, 64);
    c8[6] = __shfl_xor(a4[1], 2, 64);
    c8[7] = __shfl_xor(a4[0], 2, 64);
    BM8(c8);

    // ---- mask-4: merge two asc-8s, keep 10 of 16 (BIG-pad anti-diagonal
    //      window -> cyclically-bitonic 10 -> SORT10) ----
    float ml[KNN];
    {
        float B8[8];
#pragma unroll
        for (int k = 0; k < 8; ++k) B8[k] = __shfl_xor(c8[k], 4, 64);
        ml[0] = c8[0];
        ml[1] = c8[1];
#pragma unroll
        for (int i = 2; i <= 7; ++i) ml[i] = fminf(c8[i], B8[9 - i]);
        ml[8] = B8[1];
        ml[9] = B8[0];
        SORT10(ml);
    }
    merge_round(ml, 8); merge_round(ml, 16);
    // even lanes hold q0's full top-10 (all 4096 cands), odd lanes q1's

    // ---- publish lists (lanes 0,1 of each group) ----
    if (split < 2) {
#pragma unroll
        for (int k = 0; k < KNN; ++k) qlists[group * 2 + split][k] = ml[k];
    }
    __syncthreads();

    // ---- epilogue: 2 queries per group, one per 16-lane half ----
    const int sub  = split >> 4;           // 0 or 1: which query of the pair
    const int lane = split & 15;           // 0..15 within the half
    const int qi   = qb + group * 2 + sub;
    const float4 Qe = spts[PIDX(qi)];
    const float eqx = -2.f*Qe.x, eqy = -2.f*Qe.y, eqz = -2.f*Qe.z;

    // distributed changingrate: lanes 0..9 of each half handle one neighbor
    float crk = 0.0f;
    if (lane < KNN) {
        int j = (int)(__float_as_uint(qlists[group * 2 + sub][lane]) & 0xFFFu);
        float nx = xb[qi*6+3], ny = xb[qi*6+4], nz = xb[qi*6+5];
        float mx = xb[j*6+3],  my_ = xb[j*6+4],  mz = xb[j*6+5];
        float cx = ny*mz - nz*my_;
        float cy = nz*mx - nx*mz;
        float cz = nx*my_ - ny*mx;
        float c1 = sqrtf(cx*cx + cy*cy + cz*cz);
        float px = nx*mx, py = ny*my_, pz = nz*mz;
        float c2 = sqrtf(px*px + py*py + pz*pz);
        crk = fminf(c1, c2);
    }
#pragma unroll
    for (int m = 1; m <= 8; m <<= 1) crk += __shfl_xor(crk, m, 64);

    // top-2 skeleton scores for qi (16-lane split per query)
    float t0v = BIG, t1v = BIG;
    for (int m = lane; m < NSKEL; m += 16) {
        float4 c = sskl[m];
        float s = fmaf(eqz, c.z, fmaf(eqy, c.y, fmaf(eqx, c.x, c.w)));
        t1v = med3f(s, t0v, t1v);    // uses old t0v
        t0v = fminf(s, t0v);
    }
#pragma unroll
    for (int m = 1; m <= 8; m <<= 1) {
        float o0 = __shfl_xor(t0v, m, 64);
        float o1 = __shfl_xor(t1v, m, 64);
        float nv = fminf(fmaxf(t0v, o0), fminf(t1v, o1));
        t0v = fminf(t0v, o0); t1v = nv;
    }
    // d2 gap == score gap; owners: lane 0 of each 16-half (split 0 and 16)
    float contrib = (lane == 0) ? crk * (t1v - t0v) : 0.0f;
    contrib += __shfl_down(contrib, 16);   // half-owners -> group slots 0, 32
    contrib += __shfl_down(contrib, 32);   // -> wave lane 0
    if ((tid & 63) == 0) part[tid >> 6] = contrib;
    __syncthreads();
    if (tid == 0) {
        float s = 0.0f;
#pragma unroll
        for (int i = 0; i < 16; ++i) s += part[i];
        atomicAdd(out, s);
    }

    // ---- skeleton self-NN term, one block per batch ----
    if ((blockIdx.x & 63) == 0) {
        float v = 0.0f;
        if (tid < NSKEL) {
            float4 sq = sskl[tid];
            float b0 = BIG, b1 = BIG; int i0 = 0, i1 = 0;
            for (int jj = 0; jj < NSKEL; ++jj) {
                float4 c = sskl[jj];
                float s = c.w - 2.0f*(sq.x*c.x + sq.y*c.y + sq.z*c.z);
                if (s < b0)      { b1 = b0; i1 = i0; b0 = s; i0 = jj; }
                else if (s < b1) { b1 = s; i1 = jj; }
            }
            float4 c = sskl[i1];                 // knn_skele[..., 1]
            float dx = sq.x - c.x, dy = sq.y - c.y, dz = sq.z - c.z;
            v = sqrtf(dx*dx + dy*dy + dz*dz);
        }
#pragma unroll
        for (int o = 32; o > 0; o >>= 1) v += __shfl_down(v, o);
        if ((tid & 63) == 0 && tid < 128) atomicAdd(out, -0.5f * v);
    }
}

extern "C" void kernel_launch(void* const* d_in, const int* in_sizes, int n_in,
                              void* d_out, int out_size, void* d_ws, size_t ws_size,
                              hipStream_t stream) {
    const float* xyz  = (const float*)d_in[0];
    // d_in[1] = num_class (== NSKEL), compile-time constant here
    const float* skel = (const float*)d_in[2];
    float* out = (float*)d_out;

    hipMemsetAsync(out, 0, sizeof(float), stream);
    voronoi_kernel<<<BATCH * 64, 1024, 0, stream>>>(xyz, skel, out);
}

// Round 20
// 35.070 us; speedup vs baseline: 1.0702x; 1.0702x over previous
//
#include <hip/hip_runtime.h>

#define BATCH  4
#define NPTS   4096
#define NSKEL  100
#define KNN    10
#define KL     2                  // per-lane list length
#define QPB    64                 // queries per block (32 groups x 2)
#define CPT    128                // candidates per thread (32 chunks cover 4096)
#define CPAD   129                // padded chunk stride in float4s (129%8=1: bank de-conflict)
#define BIG    3.0e38f

__device__ __forceinline__ float med3f(float a, float b, float c) {
#if __has_builtin(__builtin_amdgcn_fmed3f)
    return __builtin_amdgcn_fmed3f(a, b, c);
#else
    float d;
    asm("v_med3_f32 %0, %1, %2, %3" : "=v"(d) : "v"(a), "v"(b), "v"(c));
    return d;
#endif
}

#define CE(a,i,j) do { float _lo = fminf(a[i],a[j]); a[j] = fmaxf(a[i],a[j]); a[i] = _lo; } while (0)
// Sorts any (cyclically-)bitonic 10-seq (validated R3-R18, absmax 0 throughout)
#define SORT10(c) do { \
    CE(c,0,8); CE(c,1,9); \
    CE(c,2,6); CE(c,3,7); CE(c,4,8); CE(c,5,9); \
    CE(c,2,4); CE(c,3,5); CE(c,6,8); CE(c,7,9); CE(c,0,1); \
    CE(c,2,3); CE(c,4,5); CE(c,6,7); CE(c,8,9); } while (0)
// Bitonic merger BM(8): sorts any bitonic 8-seq (3 stages, 12 CE)
#define BM8(c) do { \
    CE(c,0,4); CE(c,1,5); CE(c,2,6); CE(c,3,7); \
    CE(c,0,2); CE(c,1,3); CE(c,4,6); CE(c,5,7); \
    CE(c,0,1); CE(c,2,3); CE(c,4,5); CE(c,6,7); } while (0)
// Bitonic merger BM(4): sorts any bitonic 4-seq (2 stages, 4 CE)
#define BM4(c) do { \
    CE(c,0,2); CE(c,1,3); \
    CE(c,0,1); CE(c,2,3); } while (0)

// Half-cleaner merge of two ascending 10-lists (keep 10 smallest) + re-sort.
__device__ __forceinline__ void merge_round(float l[KNN], int mask) {
    float c[KNN];
#pragma unroll
    for (int i = 0; i < KNN; ++i) {
        float o = __shfl_xor(l[KNN - 1 - i], mask, 64);
        c[i] = fminf(l[i], o);
    }
    SORT10(c);
#pragma unroll
    for (int i = 0; i < KNN; ++i) l[i] = c[i];
}

// padded float4 index for global point id i (chunk i>>7 gets +1 float4 each)
#define PIDX(i) ((i) + ((i) >> 7))

__global__ __launch_bounds__(1024) void voronoi_kernel(const float* __restrict__ xyz,
                                                       const float* __restrict__ skel,
                                                       float* __restrict__ out) {
    __shared__ float4 spts[NPTS + 32];   // AoS x,y,z,|p|^2, padded: 64.5 KB
    __shared__ float4 sskl[NSKEL];
    __shared__ float  qlists[QPB][KNN];
    __shared__ float  part[16];

    const int tid = threadIdx.x;
    const int b   = blockIdx.x >> 6;           // 64 blocks per batch
    const int qb  = (blockIdx.x & 63) * QPB;   // 64 queries per block
    const float* xb = xyz  + (size_t)b * NPTS * 6;
    const float* sb = skel + (size_t)b * NSKEL * 3;

    // Stage 2 points per iter via 3 coalesced float4 loads (2 iterations)
    for (int p2 = tid; p2 < NPTS / 2; p2 += 1024) {
        const float4* row = (const float4*)(xb + p2 * 12);
        float4 A = row[0], Bv = row[1], Cv = row[2];
        int i0 = 2 * p2;           // even: i0, i0+1 share a chunk
        spts[PIDX(i0)]     = make_float4(A.x, A.y, A.z,
                                         fmaf(A.z, A.z, fmaf(A.y, A.y, A.x * A.x)));
        spts[PIDX(i0 + 1)] = make_float4(Bv.z, Bv.w, Cv.x,
                                         fmaf(Cv.x, Cv.x, fmaf(Bv.w, Bv.w, Bv.z * Bv.z)));
    }
    if (tid < NSKEL) {
        float x = sb[tid*3+0], y = sb[tid*3+1], z = sb[tid*3+2];
        sskl[tid] = make_float4(x, y, z, x*x + y*y + z*z);
    }
    __syncthreads();

    const int split = tid & 31;
    const int group = tid >> 5;            // 0..31
    const int q0i   = qb + group * 2;
    const float4 Q0 = spts[PIDX(q0i)];
    const float4 Q1 = spts[PIDX(q0i + 1)];
    // score = |c|^2 - 2 q.c (monotone map of d2; d2 gap == score gap)
    const float n0x = -2.f*Q0.x, n0y = -2.f*Q0.y, n0z = -2.f*Q0.z;
    const float n1x = -2.f*Q1.x, n1y = -2.f*Q1.y, n1z = -2.f*Q1.z;

    float l0[KL], l1[KL];
#pragma unroll
    for (int k = 0; k < KL; ++k) { l0[k] = BIG; l1[k] = BIG; }

    const int ch = split;                  // chunk 0..31
    const unsigned jbc = (unsigned)(ch << 7);
    const unsigned HMASK = 0xFFFFF000u;
    const float4* chunk = spts + ch * CPAD;  // base bank phase-distinct per 8 ch

    // Fully-unrolled scan; 1 ds_read_b128 per candidate, static offsets.
#pragma unroll
    for (int g = 0; g < CPT; ++g) {
        float4 cc = chunk[g];
        float s0 = fmaf(n0z, cc.z, fmaf(n0y, cc.y, fmaf(n0x, cc.x, cc.w)));
        float s1 = fmaf(n1z, cc.z, fmaf(n1y, cc.y, fmaf(n1x, cc.x, cc.w)));
        unsigned j = jbc | (unsigned)g;
        float f0 = __uint_as_float((__float_as_uint(s0) & HMASK) | j);
        float f1 = __uint_as_float((__float_as_uint(s1) & HMASK) | j);
        // KL=2 branchless insert (slots use OLD values)
        l0[1] = med3f(f0, l0[0], l0[1]);
        l0[0] = fminf(f0, l0[0]);
        l1[1] = med3f(f1, l1[0], l1[1]);
        l1[0] = fminf(f1, l1[0]);
    }

    // ---- mask-1: concat my asc-2 + neighbor desc-2 (both queries), select
    //      parity, then ONE BM4 -> sorted-4 for my query over 256 cands ----
    float d0[4], d1[4];
    d0[0] = l0[0]; d0[1] = l0[1];
    d0[2] = __shfl_xor(l0[1], 1, 64);
    d0[3] = __shfl_xor(l0[0], 1, 64);
    d1[0] = l1[0]; d1[1] = l1[1];
    d1[2] = __shfl_xor(l1[1], 1, 64);
    d1[3] = __shfl_xor(l1[0], 1, 64);
    const int sel = split & 1;
    float a4[4];
#pragma unroll
    for (int k = 0; k < 4; ++k) a4[k] = sel ? d1[k] : d0[k];
    BM4(a4);

    // ---- mask-2: concat two asc-4s -> bitonic-8 -> BM8 (sorted-8, 512 cands)
    float c8[8];
    c8[0] = a4[0]; c8[1] = a4[1]; c8[2] = a4[2]; c8[3] = a4[3];
    c8[4] = __shfl_xor(a4[3], 2, 64);
    c8[5] = __shfl_xor(a4[2], 2, 64);
    c8[6] = __shfl_xor(a4[1], 2, 64);
    c8[7] = __shfl_xor(a4[0], 2, 64);
    BM8(c8);

    // ---- mask-4: merge two asc-8s, keep 10 of 16 (BIG-pad anti-diagonal
    //      window -> cyclically-bitonic 10 -> SORT10) ----
    float ml[KNN];
    {
        float B8[8];
#pragma unroll
        for (int k = 0; k < 8; ++k) B8[k] = __shfl_xor(c8[k], 4, 64);
        ml[0] = c8[0];
        ml[1] = c8[1];
#pragma unroll
        for (int i = 2; i <= 7; ++i) ml[i] = fminf(c8[i], B8[9 - i]);
        ml[8] = B8[1];
        ml[9] = B8[0];
        SORT10(ml);
    }
    merge_round(ml, 8); merge_round(ml, 16);
    // even lanes hold q0's full top-10 (all 4096 cands), odd lanes q1's

    // ---- publish lists (lanes 0,1 of each group) ----
    if (split < 2) {
#pragma unroll
        for (int k = 0; k < KNN; ++k) qlists[group * 2 + split][k] = ml[k];
    }
    __syncthreads();

    // ---- epilogue: 2 queries per group, one per 16-lane half ----
    const int sub  = split >> 4;           // 0 or 1: which query of the pair
    const int lane = split & 15;           // 0..15 within the half
    const int qi   = qb + group * 2 + sub;
    const float4 Qe = spts[PIDX(qi)];
    const float eqx = -2.f*Qe.x, eqy = -2.f*Qe.y, eqz = -2.f*Qe.z;

    // distributed changingrate: lanes 0..9 of each half handle one neighbor
    float crk = 0.0f;
    if (lane < KNN) {
        int j = (int)(__float_as_uint(qlists[group * 2 + sub][lane]) & 0xFFFu);
        float nx = xb[qi*6+3], ny = xb[qi*6+4], nz = xb[qi*6+5];
        float mx = xb[j*6+3],  my_ = xb[j*6+4],  mz = xb[j*6+5];
        float cx = ny*mz - nz*my_;
        float cy = nz*mx - nx*mz;
        float cz = nx*my_ - ny*mx;
        float c1 = sqrtf(cx*cx + cy*cy + cz*cz);
        float px = nx*mx, py = ny*my_, pz = nz*mz;
        float c2 = sqrtf(px*px + py*py + pz*pz);
        crk = fminf(c1, c2);
    }
#pragma unroll
    for (int m = 1; m <= 8; m <<= 1) crk += __shfl_xor(crk, m, 64);

    // top-2 skeleton scores for qi (16-lane split per query)
    float t0v = BIG, t1v = BIG;
    for (int m = lane; m < NSKEL; m += 16) {
        float4 c = sskl[m];
        float s = fmaf(eqz, c.z, fmaf(eqy, c.y, fmaf(eqx, c.x, c.w)));
        t1v = med3f(s, t0v, t1v);    // uses old t0v
        t0v = fminf(s, t0v);
    }
#pragma unroll
    for (int m = 1; m <= 8; m <<= 1) {
        float o0 = __shfl_xor(t0v, m, 64);
        float o1 = __shfl_xor(t1v, m, 64);
        float nv = fminf(fmaxf(t0v, o0), fminf(t1v, o1));
        t0v = fminf(t0v, o0); t1v = nv;
    }
    // d2 gap == score gap; owners: lane 0 of each 16-half (split 0 and 16)
    float contrib = (lane == 0) ? crk * (t1v - t0v) : 0.0f;
    contrib += __shfl_down(contrib, 16);   // half-owners -> group slots 0, 32
    contrib += __shfl_down(contrib, 32);   // -> wave lane 0
    if ((tid & 63) == 0) part[tid >> 6] = contrib;
    __syncthreads();
    if (tid == 0) {
        float s = 0.0f;
#pragma unroll
        for (int i = 0; i < 16; ++i) s += part[i];
        atomicAdd(out, s);
    }

    // ---- skeleton self-NN term, one block per batch ----
    if ((blockIdx.x & 63) == 0) {
        float v = 0.0f;
        if (tid < NSKEL) {
            float4 sq = sskl[tid];
            float b0 = BIG, b1 = BIG; int i0 = 0, i1 = 0;
            for (int jj = 0; jj < NSKEL; ++jj) {
                float4 c = sskl[jj];
                float s = c.w - 2.0f*(sq.x*c.x + sq.y*c.y + sq.z*c.z);
                if (s < b0)      { b1 = b0; i1 = i0; b0 = s; i0 = jj; }
                else if (s < b1) { b1 = s; i1 = jj; }
            }
            float4 c = sskl[i1];                 // knn_skele[..., 1]
            float dx = sq.x - c.x, dy = sq.y - c.y, dz = sq.z - c.z;
            v = sqrtf(dx*dx + dy*dy + dz*dz);
        }
#pragma unroll
        for (int o = 32; o > 0; o >>= 1) v += __shfl_down(v, o);
        if ((tid & 63) == 0 && tid < 128) atomicAdd(out, -0.5f * v);
    }
}

extern "C" void kernel_launch(void* const* d_in, const int* in_sizes, int n_in,
                              void* d_out, int out_size, void* d_ws, size_t ws_size,
                              hipStream_t stream) {
    const float* xyz  = (const float*)d_in[0];
    // d_in[1] = num_class (== NSKEL), compile-time constant here
    const float* skel = (const float*)d_in[2];
    float* out = (float*)d_out;

    hipMemsetAsync(out, 0, sizeof(float), stream);
    voronoi_kernel<<<BATCH * 64, 1024, 0, stream>>>(xyz, skel, out);
}